// Round 19
// baseline (121.534 us; speedup 1.0000x reference)
//
#include <hip/hip_runtime.h>
#include <stdint.h>
#include <stddef.h>

// MultiHeadAttention: B=2, S=2048, D=1024, H=16, kd=64. All inputs fp32.
// Pipeline (R18 + attn 2-wave blocks):
//   convert_all : fp32 -> bf16 once. Wq pre-scaled by 0.125*log2(e).
//   proj_gemm   : bf16 NT GEMM, BK=32 ring-3 + counted-vmcnt + granule swizzle.
//                 Grid (32,8,3): XCD = m%8 pins each A-panel to one XCD L2.
//   attn_kernel : R14-exact per-wave body, but QBLK=64 / 2-wave (128-thread)
//                 blocks -> 1024 blocks = 4/CU, barrier groups halved; waves
//                 from independent blocks cover each other's phase stalls.
//                 Grid (32,32): XCD = bh%8 pins each head's K/V to one XCD L2.
//   out_gemm    : bf16 NT GEMM (BM=64), ring-3 + swizzle. Grid (64,8).
//
// ws layout (bf16 elements): [valueb/X 4M | W4 4M | Qp 4M | Kp 4M | Vt 4M] = 40 MB
// d_out scratch during proj: [queryb 4M | keyb 4M]; X aliases valueb.

typedef __attribute__((ext_vector_type(8))) short short8;
typedef __attribute__((ext_vector_type(4))) float floatx4;
typedef __attribute__((ext_vector_type(16))) float f32x16;
typedef __attribute__((ext_vector_type(4))) unsigned short ushort4v;

#define MFMA16(a, b, c) __builtin_amdgcn_mfma_f32_16x16x32_bf16((a), (b), (c), 0, 0, 0)
#define MFMA32(a, b, c) __builtin_amdgcn_mfma_f32_32x32x16_bf16((a), (b), (c), 0, 0, 0)

#define CL2 0.18033688011112042f  // 0.125 * log2(e)

__device__ __forceinline__ unsigned short f2bf(float f) {
  union { float f; unsigned u; } v; v.f = f;
  unsigned u = v.u;
  return (unsigned short)((u + 0x7fffu + ((u >> 16) & 1u)) >> 16); // RTNE
}

__device__ __forceinline__ float fast_exp2(float x) {
  float r;
  asm("v_exp_f32 %0, %1" : "=v"(r) : "v"(x));
  return r;
}

__device__ __forceinline__ unsigned cvt_pk_bf16(float lo, float hi) {
  unsigned r;
  asm("v_cvt_pk_bf16_f32 %0, %1, %2" : "=v"(r) : "v"(lo), "v"(hi));
  return r;
}

#define PSWAP(a, b) asm("v_permlane32_swap_b32 %0, %1" : "+v"(a), "+v"(b))

// counted-vmcnt barrier (GEMMs: reads consumed same-interval, no spills at
// VGPR~110 so the vmcnt count is exact).
#define WAITBAR(N) do { \
  asm volatile("s_waitcnt vmcnt(" #N ")" ::: "memory"); \
  __builtin_amdgcn_s_barrier(); \
  __builtin_amdgcn_sched_barrier(0); \
} while (0)

union B8 { unsigned short s[8]; short8 v; };
union U4 { unsigned w[4]; short8 v; };

__device__ __forceinline__ void gload_lds16(const unsigned short* g, unsigned short* l) {
  __builtin_amdgcn_global_load_lds(
      (__attribute__((address_space(1))) void*)(g),
      (__attribute__((address_space(3))) void*)(l), 16, 0, 0);
}

// ---------------------------------------------------------------------------
// convert_all: fp32 -> bf16, 8 elems/thread. Wq region scaled by CL2.
// ---------------------------------------------------------------------------
__global__ __launch_bounds__(256) void convert_all(
    const float* __restrict__ q, const float* __restrict__ k, const float* __restrict__ v,
    const float* __restrict__ wq, const float* __restrict__ wk,
    const float* __restrict__ wv, const float* __restrict__ wo,
    unsigned short* __restrict__ qb, unsigned short* __restrict__ kb,
    unsigned short* __restrict__ vb, unsigned short* __restrict__ w4)
{
  int b = blockIdx.x;
  const float* s; unsigned short* d;
  float sc = 1.0f;
  if (b < 2048)      { s = q;  d = qb; }
  else if (b < 4096) { s = k;  d = kb; b -= 2048; }
  else if (b < 6144) { s = v;  d = vb; b -= 4096; }
  else if (b < 6656) { s = wq; d = w4;            b -= 6144; sc = CL2; }
  else if (b < 7168) { s = wk; d = w4 + 1048576;  b -= 6656; }
  else if (b < 7680) { s = wv; d = w4 + 2097152;  b -= 7168; }
  else               { s = wo; d = w4 + 3145728;  b -= 7680; }
  const size_t i = ((size_t)b * 256 + threadIdx.x) * 8;
  float4 f0 = *(const float4*)(s + i);
  float4 f1 = *(const float4*)(s + i + 4);
  B8 u;
  u.s[0] = f2bf(f0.x * sc); u.s[1] = f2bf(f0.y * sc);
  u.s[2] = f2bf(f0.z * sc); u.s[3] = f2bf(f0.w * sc);
  u.s[4] = f2bf(f1.x * sc); u.s[5] = f2bf(f1.y * sc);
  u.s[6] = f2bf(f1.z * sc); u.s[7] = f2bf(f1.w * sc);
  *(short8*)(d + i) = u.v;
}

// ---------------------------------------------------------------------------
// proj_gemm: C = A*W^T + bias. 128x128 tile, BK=32, ring-3 LDS, counted vmcnt,
// granule swizzle g^=(row>>1)&3. Grid (32,8,3): m on x (XCD-pinned A panels).
// z=0: queryb->Qp (pre-scaled CL2), z=1: keyb->Kp, z=2: valueb->Vt (transposed).
// ---------------------------------------------------------------------------
__global__ __launch_bounds__(256) void proj_gemm(
    const unsigned short* __restrict__ A0, const unsigned short* __restrict__ A1,
    const unsigned short* __restrict__ A2, const unsigned short* __restrict__ W4,
    const float* __restrict__ b0, const float* __restrict__ b1, const float* __restrict__ b2,
    unsigned short* __restrict__ Qp, unsigned short* __restrict__ Kp,
    unsigned short* __restrict__ Vt)
{
  const int z = blockIdx.z;
  const unsigned short* A = (z == 0) ? A0 : ((z == 1) ? A1 : A2);
  const unsigned short* W = W4 + (size_t)z * 1048576;
  const float* bias = (z == 0) ? b0 : ((z == 1) ? b1 : b2);
  const float esc = (z == 0) ? CL2 : 1.0f;

  const int m0 = blockIdx.x * 128;   // x = m: XCD = m%8 -> A panel pinned
  const int n0 = blockIdx.y * 128;
  const int tid = threadIdx.x;
  const int lane = tid & 63;
  const int wid = tid >> 6;
  const int wr = wid >> 1, wc = wid & 1;
  const int g = lane >> 4, l15 = lane & 15;

  __shared__ unsigned short As[3][128 * 32];
  __shared__ unsigned short Bs[3][128 * 32];

  const floatx4 vzero = {0.f, 0.f, 0.f, 0.f};
  floatx4 acc[4][4];
#pragma unroll
  for (int i = 0; i < 4; ++i)
#pragma unroll
    for (int j = 0; j < 4; ++j) acc[i][j] = vzero;

  const int lr = lane >> 2;
  const int rb0 = wid * 16, rb1 = (4 + wid) * 16;
  const int gsw0 = ((lane & 3) ^ (((rb0 + lr) >> 1) & 3)) * 8;
  const int gsw1 = ((lane & 3) ^ (((rb1 + lr) >> 1) & 3)) * 8;
  const unsigned short* pa0 = &A[(size_t)(m0 + rb0 + lr) * 1024 + gsw0];
  const unsigned short* pa1 = &A[(size_t)(m0 + rb1 + lr) * 1024 + gsw1];
  const unsigned short* pw0 = &W[(size_t)(n0 + rb0 + lr) * 1024 + gsw0];
  const unsigned short* pw1 = &W[(size_t)(n0 + rb1 + lr) * 1024 + gsw1];

#define PSTAGE(s_, b_) do { \
    gload_lds16(pa0 + (s_) * 32, &As[b_][rb0 * 32]); \
    gload_lds16(pa1 + (s_) * 32, &As[b_][rb1 * 32]); \
    gload_lds16(pw0 + (s_) * 32, &Bs[b_][rb0 * 32]); \
    gload_lds16(pw1 + (s_) * 32, &Bs[b_][rb1 * 32]); \
  } while (0)

  PSTAGE(0, 0);
  PSTAGE(1, 1);

  int cur = 0;
  for (int s = 0; s < 32; ++s) {
    if (s < 31) WAITBAR(4); else WAITBAR(0);
    if (s + 2 < 32) {
      int nb = cur + 2; if (nb >= 3) nb -= 3;
      PSTAGE(s + 2, nb);
    }

    short8 af[4], bfr[4];
#pragma unroll
    for (int mt = 0; mt < 4; ++mt) {
      const int R = wr * 64 + mt * 16 + l15;
      af[mt] = *(const short8*)&As[cur][R * 32 + ((g ^ ((R >> 1) & 3)) * 8)];
    }
#pragma unroll
    for (int nt = 0; nt < 4; ++nt) {
      const int R = wc * 64 + nt * 16 + l15;
      bfr[nt] = *(const short8*)&Bs[cur][R * 32 + ((g ^ ((R >> 1) & 3)) * 8)];
    }

    __builtin_amdgcn_s_setprio(1);
#pragma unroll
    for (int mt = 0; mt < 4; ++mt)
#pragma unroll
      for (int nt = 0; nt < 4; ++nt)
        acc[mt][nt] = MFMA16(af[mt], bfr[nt], acc[mt][nt]);
    __builtin_amdgcn_s_setprio(0);

    cur = (cur + 1 == 3) ? 0 : cur + 1;
  }
#undef PSTAGE

  float bvv[4];
#pragma unroll
  for (int nt = 0; nt < 4; ++nt) bvv[nt] = bias[n0 + wc * 64 + nt * 16 + l15] * esc;

  if (z < 2) {
    unsigned short* dst = (z == 0) ? Qp : Kp;
#pragma unroll
    for (int mt = 0; mt < 4; ++mt)
#pragma unroll
      for (int r = 0; r < 4; ++r) {
        const size_t row = (size_t)(m0 + wr * 64 + mt * 16 + g * 4 + r);
#pragma unroll
        for (int nt = 0; nt < 4; ++nt)
          dst[row * 1024 + n0 + wc * 64 + nt * 16 + l15] =
              f2bf(acc[mt][nt][r] + bvv[nt]);
      }
  } else {
#pragma unroll
    for (int mt = 0; mt < 4; ++mt) {
      const int sr = m0 + wr * 64 + mt * 16 + g * 4;
      const int bb = sr >> 11;
      const int ss = sr & 2047;
#pragma unroll
      for (int nt = 0; nt < 4; ++nt) {
        const int n = n0 + wc * 64 + nt * 16 + l15;
        const int hh = n >> 6, dd = n & 63;
        ushort4v o;
#pragma unroll
        for (int r = 0; r < 4; ++r) o[r] = f2bf(acc[mt][nt][r] + bvv[nt]);
        *(ushort4v*)&Vt[((size_t)(bb * 16 + hh) * 64 + dd) * 2048 + ss] = o;
      }
    }
  }
}

// ---------------------------------------------------------------------------
// attn_kernel: R14-exact per-wave body; 2 waves x 32 q-rows (QBLK=64),
// KVBLK=64, 32x32x16, sync-dbuf, chain-split, exp2-domain, no max tracking.
// Grid (32,32): bh on x (XCD-pinned K/V); 1024 blocks = 4/CU.
// Staging: 128 threads x 4 K-slots + 4 V-slots (wave-uniform dest bases).
// ---------------------------------------------------------------------------
__global__ __launch_bounds__(128, 2) void attn_kernel(
    const unsigned short* __restrict__ Qp, const unsigned short* __restrict__ Kp,
    const unsigned short* __restrict__ Vt, unsigned short* __restrict__ X)
{
  const int bh = blockIdx.x;   // 0..31 (XCD-pinning dimension)
  const int qb = blockIdx.y;   // 0..31 (64 q-rows per block)
  const int b = bh >> 4, h = bh & 15;
  const int tid = threadIdx.x, lane = tid & 63, w = tid >> 6;  // w in {0,1}
  const int l31 = lane & 31, hi = lane >> 5;

  __shared__ unsigned short KV[2][2][4096];  // [buf][K/V][64 x 64], swizzled

  const int qrow = b * 2048 + qb * 64 + w * 32 + l31;
  short8 Qf[4];
#pragma unroll
  for (int ks = 0; ks < 4; ++ks)
    Qf[ks] = *(const short8*)&Qp[(size_t)qrow * 1024 + h * 64 + ks * 16 + hi * 8];

  // staging: slot = e*128 + tid (e=0..3); row = slot>>3; gran = (slot&7)^(row&7)
  int srow[4], sgr[4];
#pragma unroll
  for (int e = 0; e < 4; ++e) {
    const int slot = e * 128 + tid;
    srow[e] = slot >> 3;
    sgr[e] = ((slot & 7) ^ (srow[e] & 7)) * 8;
  }
  const unsigned short* kq[4];
  const unsigned short* vq[4];
#pragma unroll
  for (int e = 0; e < 4; ++e) {
    kq[e] = Kp + (size_t)(b * 2048 + srow[e]) * 1024 + h * 64 + sgr[e];
    vq[e] = Vt + (size_t)(bh * 64 + srow[e]) * 2048 + sgr[e];
  }

#define ASTAGE(t_, b_) do { \
    const size_t ko = (size_t)(t_) * 65536, vo = (size_t)(t_) * 64; \
    _Pragma("unroll") \
    for (int e = 0; e < 4; ++e) { \
      gload_lds16(kq[e] + ko, &KV[b_][0][(e * 128 + w * 64) * 8]); \
      gload_lds16(vq[e] + vo, &KV[b_][1][(e * 128 + w * 64) * 8]); \
    } \
  } while (0)

  f32x16 o0a, o0b, o1a, o1b;
#pragma unroll
  for (int i = 0; i < 16; ++i) { o0a[i] = 0.f; o0b[i] = 0.f; o1a[i] = 0.f; o1b[i] = 0.f; }
  float lp4[4] = {0.f, 0.f, 0.f, 0.f};

  ASTAGE(0, 0);
  __syncthreads();

  int cur = 0;
  for (int t = 0; t < 32; ++t) {
    if (t + 1 < 32) ASTAGE(t + 1, cur ^ 1);
    const unsigned short* Kb = &KV[cur][0][0];
    const unsigned short* Vb = &KV[cur][1][0];

    f32x16 c0a, c0b, c1a, c1b;
#pragma unroll
    for (int i = 0; i < 16; ++i) { c0a[i] = 0.f; c0b[i] = 0.f; c1a[i] = 0.f; c1b[i] = 0.f; }
    {
      const int kx = l31 & 7;
      const int base0 = l31 * 64;
      const int base1 = (32 + l31) * 64;
      short8 kf00 = *(const short8*)&Kb[base0 + (((0 + hi) ^ kx) << 3)];
      short8 kf01 = *(const short8*)&Kb[base0 + (((2 + hi) ^ kx) << 3)];
      short8 kf02 = *(const short8*)&Kb[base0 + (((4 + hi) ^ kx) << 3)];
      short8 kf03 = *(const short8*)&Kb[base0 + (((6 + hi) ^ kx) << 3)];
      short8 kf10 = *(const short8*)&Kb[base1 + (((0 + hi) ^ kx) << 3)];
      short8 kf11 = *(const short8*)&Kb[base1 + (((2 + hi) ^ kx) << 3)];
      short8 kf12 = *(const short8*)&Kb[base1 + (((4 + hi) ^ kx) << 3)];
      short8 kf13 = *(const short8*)&Kb[base1 + (((6 + hi) ^ kx) << 3)];
      __builtin_amdgcn_s_setprio(1);
      c0a = MFMA32(kf00, Qf[0], c0a); c0a = MFMA32(kf01, Qf[1], c0a);
      c0b = MFMA32(kf02, Qf[2], c0b); c0b = MFMA32(kf03, Qf[3], c0b);
      c1a = MFMA32(kf10, Qf[0], c1a); c1a = MFMA32(kf11, Qf[1], c1a);
      c1b = MFMA32(kf12, Qf[2], c1b); c1b = MFMA32(kf13, Qf[3], c1b);
      __builtin_amdgcn_s_setprio(0);
    }

    short8 vf0[4], vf1[4];
    {
      const int kx = l31 & 7;
      const int vrow1 = 32 + l31;
#pragma unroll
      for (int ks = 0; ks < 4; ++ks) {
        vf0[ks] = *(const short8*)&Vb[l31 * 64 + (((ks * 2 + hi) ^ kx) << 3)];
        vf1[ks] = *(const short8*)&Vb[vrow1 * 64 + (((ks * 2 + hi) ^ (vrow1 & 7)) << 3)];
      }
    }

#pragma unroll
    for (int i = 0; i < 16; ++i) {
      const float p = fast_exp2(c0a[i] + c0b[i]);
      c0a[i] = p; lp4[i & 3] += p;
    }
#pragma unroll
    for (int i = 0; i < 16; ++i) {
      const float p = fast_exp2(c1a[i] + c1b[i]);
      c1a[i] = p; lp4[i & 3] += p;
    }

    short8 PA0, PA1, PA2, PA3;
    {
      unsigned p0 = cvt_pk_bf16(c0a[0], c0a[1]),   p1 = cvt_pk_bf16(c0a[2], c0a[3]);
      unsigned p2 = cvt_pk_bf16(c0a[4], c0a[5]),   p3 = cvt_pk_bf16(c0a[6], c0a[7]);
      unsigned p4 = cvt_pk_bf16(c0a[8], c0a[9]),   p5 = cvt_pk_bf16(c0a[10], c0a[11]);
      unsigned p6 = cvt_pk_bf16(c0a[12], c0a[13]), p7 = cvt_pk_bf16(c0a[14], c0a[15]);
      PSWAP(p0, p2); PSWAP(p1, p3); PSWAP(p4, p6); PSWAP(p5, p7);
      U4 a_, b_;
      a_.w[0] = p0; a_.w[1] = p1; a_.w[2] = p2; a_.w[3] = p3;      PA0 = a_.v;
      b_.w[0] = p4; b_.w[1] = p5; b_.w[2] = p6; b_.w[3] = p7;      PA1 = b_.v;
    }
    {
      unsigned p0 = cvt_pk_bf16(c1a[0], c1a[1]),   p1 = cvt_pk_bf16(c1a[2], c1a[3]);
      unsigned p2 = cvt_pk_bf16(c1a[4], c1a[5]),   p3 = cvt_pk_bf16(c1a[6], c1a[7]);
      unsigned p4 = cvt_pk_bf16(c1a[8], c1a[9]),   p5 = cvt_pk_bf16(c1a[10], c1a[11]);
      unsigned p6 = cvt_pk_bf16(c1a[12], c1a[13]), p7 = cvt_pk_bf16(c1a[14], c1a[15]);
      PSWAP(p0, p2); PSWAP(p1, p3); PSWAP(p4, p6); PSWAP(p5, p7);
      U4 a_, b_;
      a_.w[0] = p0; a_.w[1] = p1; a_.w[2] = p2; a_.w[3] = p3;      PA2 = a_.v;
      b_.w[0] = p4; b_.w[1] = p5; b_.w[2] = p6; b_.w[3] = p7;      PA3 = b_.v;
    }

    __builtin_amdgcn_s_setprio(1);
    o0a = MFMA32(vf0[0], PA0, o0a); o0a = MFMA32(vf0[1], PA1, o0a);
    o0b = MFMA32(vf0[2], PA2, o0b); o0b = MFMA32(vf0[3], PA3, o0b);
    o1a = MFMA32(vf1[0], PA0, o1a); o1a = MFMA32(vf1[1], PA1, o1a);
    o1b = MFMA32(vf1[2], PA2, o1b); o1b = MFMA32(vf1[3], PA3, o1b);
    __builtin_amdgcn_s_setprio(0);

    __syncthreads();
    cur ^= 1;
  }
#undef ASTAGE

  const float l_run = (lp4[0] + lp4[1]) + (lp4[2] + lp4[3]);
  const float l_tot = l_run + __shfl_xor(l_run, 32);
  const float linv = 1.f / l_tot;
#pragma unroll
  for (int a = 0; a < 4; ++a) {
    ushort4v v0, v1;
#pragma unroll
    for (int r = 0; r < 4; ++r) {
      v0[r] = f2bf((o0a[a * 4 + r] + o0b[a * 4 + r]) * linv);
      v1[r] = f2bf((o1a[a * 4 + r] + o1b[a * 4 + r]) * linv);
    }
    *(ushort4v*)&X[(size_t)qrow * 1024 + h * 64 + a * 8 + hi * 4] = v0;
    *(ushort4v*)&X[(size_t)qrow * 1024 + h * 64 + 32 + a * 8 + hi * 4] = v1;
  }
}

// ---------------------------------------------------------------------------
// out_gemm: out = X*Wo^T + bo (fp32). BM=64, BN=128, BK=32 ring-3, counted
// vmcnt(3), granule swizzle. Grid (64,8): m on x (XCD-pinned X panels).
// ---------------------------------------------------------------------------
__global__ __launch_bounds__(256) void out_gemm(
    const unsigned short* __restrict__ A, const unsigned short* __restrict__ W,
    const float* __restrict__ bias, float* __restrict__ out)
{
  const int m0 = blockIdx.x * 64;    // x = m: XCD-pinned X panels
  const int n0 = blockIdx.y * 128;
  const int tid = threadIdx.x;
  const int lane = tid & 63;
  const int wid = tid >> 6;
  const int wr = wid >> 1, wc = wid & 1;
  const int g = lane >> 4, l15 = lane & 15;

  __shared__ unsigned short As[3][64 * 32];
  __shared__ unsigned short Bs[3][128 * 32];

  const floatx4 vzero = {0.f, 0.f, 0.f, 0.f};
  floatx4 acc[2][4];
#pragma unroll
  for (int i = 0; i < 2; ++i)
#pragma unroll
    for (int j = 0; j < 4; ++j) acc[i][j] = vzero;

  const int lr = lane >> 2;
  const int rb0 = wid * 16, rb1 = (4 + wid) * 16;
  const int gsw0 = ((lane & 3) ^ (((rb0 + lr) >> 1) & 3)) * 8;
  const int gsw1 = ((lane & 3) ^ (((rb1 + lr) >> 1) & 3)) * 8;
  const unsigned short* pa0 = &A[(size_t)(m0 + rb0 + lr) * 1024 + gsw0];
  const unsigned short* pw0 = &W[(size_t)(n0 + rb0 + lr) * 1024 + gsw0];
  const unsigned short* pw1 = &W[(size_t)(n0 + rb1 + lr) * 1024 + gsw1];

#define OSTAGE(s_, b_) do { \
    gload_lds16(pa0 + (s_) * 32, &As[b_][rb0 * 32]); \
    gload_lds16(pw0 + (s_) * 32, &Bs[b_][rb0 * 32]); \
    gload_lds16(pw1 + (s_) * 32, &Bs[b_][rb1 * 32]); \
  } while (0)

  OSTAGE(0, 0);
  OSTAGE(1, 1);

  int cur = 0;
  for (int s = 0; s < 32; ++s) {
    if (s < 31) WAITBAR(3); else WAITBAR(0);
    if (s + 2 < 32) {
      int nb = cur + 2; if (nb >= 3) nb -= 3;
      OSTAGE(s + 2, nb);
    }

    short8 af[2], bfr[4];
#pragma unroll
    for (int mt = 0; mt < 2; ++mt) {
      const int R = wr * 32 + mt * 16 + l15;
      af[mt] = *(const short8*)&As[cur][R * 32 + ((g ^ ((R >> 1) & 3)) * 8)];
    }
#pragma unroll
    for (int nt = 0; nt < 4; ++nt) {
      const int R = wc * 64 + nt * 16 + l15;
      bfr[nt] = *(const short8*)&Bs[cur][R * 32 + ((g ^ ((R >> 1) & 3)) * 8)];
    }

    __builtin_amdgcn_s_setprio(1);
#pragma unroll
    for (int mt = 0; mt < 2; ++mt)
#pragma unroll
      for (int nt = 0; nt < 4; ++nt)
        acc[mt][nt] = MFMA16(af[mt], bfr[nt], acc[mt][nt]);
    __builtin_amdgcn_s_setprio(0);

    cur = (cur + 1 == 3) ? 0 : cur + 1;
  }
#undef OSTAGE

  float bvv[4];
#pragma unroll
  for (int nt = 0; nt < 4; ++nt) bvv[nt] = bias[n0 + wc * 64 + nt * 16 + l15];

#pragma unroll
  for (int mt = 0; mt < 2; ++mt)
#pragma unroll
    for (int r = 0; r < 4; ++r) {
      const size_t row = (size_t)(m0 + wr * 32 + mt * 16 + g * 4 + r);
#pragma unroll
      for (int nt = 0; nt < 4; ++nt)
        out[row * 1024 + n0 + wc * 64 + nt * 16 + l15] = acc[mt][nt][r] + bvv[nt];
    }
}

// ---------------------------------------------------------------------------
extern "C" void kernel_launch(void* const* d_in, const int* in_sizes, int n_in,
                              void* d_out, int out_size, void* d_ws, size_t ws_size,
                              hipStream_t stream)
{
  const float* query = (const float*)d_in[0];
  const float* value = (const float*)d_in[1];
  const float* key   = (const float*)d_in[2];
  const float* Wq = (const float*)d_in[3];
  const float* bq = (const float*)d_in[4];
  const float* Wk = (const float*)d_in[5];
  const float* bk = (const float*)d_in[6];
  const float* Wv = (const float*)d_in[7];
  const float* bv = (const float*)d_in[8];
  const float* Wo = (const float*)d_in[9];
  const float* bo = (const float*)d_in[10];
  float* out = (float*)d_out;

  const size_t M4 = (size_t)4096 * 1024;
  unsigned short* vb = (unsigned short*)d_ws;
  unsigned short* w4 = vb + M4;
  unsigned short* Qp = w4 + M4;
  unsigned short* Kp = Qp + M4;
  unsigned short* Vt = Kp + M4;
  unsigned short* X  = vb;  // alias (valueb dead after proj)
  unsigned short* qb = (unsigned short*)d_out;  // d_out scratch
  unsigned short* kb = qb + M4;

  convert_all<<<8192, 256, 0, stream>>>(query, key, value, Wq, Wk, Wv, Wo,
                                        qb, kb, vb, w4);
  proj_gemm<<<dim3(32, 8, 3), 256, 0, stream>>>(qb, kb, vb, w4,
                                                bq, bk, bv, Qp, Kp, Vt);
  attn_kernel<<<dim3(32, 32), 128, 0, stream>>>(Qp, Kp, Vt, X);
  out_gemm<<<dim3(64, 8), 256, 0, stream>>>(X, w4 + 3 * 1048576, bo, out);
}

// Round 20
// 117.821 us; speedup vs baseline: 1.0315x; 1.0315x over previous
//
#include <hip/hip_runtime.h>
#include <stdint.h>
#include <stddef.h>

// MultiHeadAttention: B=2, S=2048, D=1024, H=16, kd=64. All inputs fp32.
// Pipeline (best-known configuration, R18):
//   convert_all : fp32 -> bf16 once. Wq pre-scaled by 0.125*log2(e).
//   proj_gemm   : bf16 NT GEMM, BK=32 ring-3 + counted-vmcnt + granule swizzle.
//                 Grid (32,8,3): XCD = m%8 pins each A-panel to one XCD L2.
//   attn_kernel : sync-dbuf flash attention (KVBLK=64, chain-split accums,
//                 exp2-domain softmax, no max-tracking, in-register P via
//                 cvt_pk+permlane). Grid (32,16): XCD = bh%8 pins K/V per head.
//   out_gemm    : bf16 NT GEMM (BM=64), ring-3 + swizzle. Grid (64,8).
//
// ws layout (bf16 elements): [valueb/X 4M | W4 4M | Qp 4M | Kp 4M | Vt 4M] = 40 MB
// d_out scratch during proj: [queryb 4M | keyb 4M]; X aliases valueb.

typedef __attribute__((ext_vector_type(8))) short short8;
typedef __attribute__((ext_vector_type(4))) float floatx4;
typedef __attribute__((ext_vector_type(16))) float f32x16;
typedef __attribute__((ext_vector_type(4))) unsigned short ushort4v;

#define MFMA16(a, b, c) __builtin_amdgcn_mfma_f32_16x16x32_bf16((a), (b), (c), 0, 0, 0)
#define MFMA32(a, b, c) __builtin_amdgcn_mfma_f32_32x32x16_bf16((a), (b), (c), 0, 0, 0)

#define CL2 0.18033688011112042f  // 0.125 * log2(e)

__device__ __forceinline__ unsigned short f2bf(float f) {
  union { float f; unsigned u; } v; v.f = f;
  unsigned u = v.u;
  return (unsigned short)((u + 0x7fffu + ((u >> 16) & 1u)) >> 16); // RTNE
}

__device__ __forceinline__ float fast_exp2(float x) {
  float r;
  asm("v_exp_f32 %0, %1" : "=v"(r) : "v"(x));
  return r;
}

__device__ __forceinline__ unsigned cvt_pk_bf16(float lo, float hi) {
  unsigned r;
  asm("v_cvt_pk_bf16_f32 %0, %1, %2" : "=v"(r) : "v"(lo), "v"(hi));
  return r;
}

#define PSWAP(a, b) asm("v_permlane32_swap_b32 %0, %1" : "+v"(a), "+v"(b))

// counted-vmcnt barrier (GEMMs: reads consumed same-interval, no spills at
// VGPR~110 so the vmcnt count is exact).
#define WAITBAR(N) do { \
  asm volatile("s_waitcnt vmcnt(" #N ")" ::: "memory"); \
  __builtin_amdgcn_s_barrier(); \
  __builtin_amdgcn_sched_barrier(0); \
} while (0)

union B8 { unsigned short s[8]; short8 v; };
union U4 { unsigned w[4]; short8 v; };

__device__ __forceinline__ void gload_lds16(const unsigned short* g, unsigned short* l) {
  __builtin_amdgcn_global_load_lds(
      (__attribute__((address_space(1))) void*)(g),
      (__attribute__((address_space(3))) void*)(l), 16, 0, 0);
}

// ---------------------------------------------------------------------------
// convert_all: fp32 -> bf16, 8 elems/thread. Wq region scaled by CL2.
// ---------------------------------------------------------------------------
__global__ __launch_bounds__(256) void convert_all(
    const float* __restrict__ q, const float* __restrict__ k, const float* __restrict__ v,
    const float* __restrict__ wq, const float* __restrict__ wk,
    const float* __restrict__ wv, const float* __restrict__ wo,
    unsigned short* __restrict__ qb, unsigned short* __restrict__ kb,
    unsigned short* __restrict__ vb, unsigned short* __restrict__ w4)
{
  int b = blockIdx.x;
  const float* s; unsigned short* d;
  float sc = 1.0f;
  if (b < 2048)      { s = q;  d = qb; }
  else if (b < 4096) { s = k;  d = kb; b -= 2048; }
  else if (b < 6144) { s = v;  d = vb; b -= 4096; }
  else if (b < 6656) { s = wq; d = w4;            b -= 6144; sc = CL2; }
  else if (b < 7168) { s = wk; d = w4 + 1048576;  b -= 6656; }
  else if (b < 7680) { s = wv; d = w4 + 2097152;  b -= 7168; }
  else               { s = wo; d = w4 + 3145728;  b -= 7680; }
  const size_t i = ((size_t)b * 256 + threadIdx.x) * 8;
  float4 f0 = *(const float4*)(s + i);
  float4 f1 = *(const float4*)(s + i + 4);
  B8 u;
  u.s[0] = f2bf(f0.x * sc); u.s[1] = f2bf(f0.y * sc);
  u.s[2] = f2bf(f0.z * sc); u.s[3] = f2bf(f0.w * sc);
  u.s[4] = f2bf(f1.x * sc); u.s[5] = f2bf(f1.y * sc);
  u.s[6] = f2bf(f1.z * sc); u.s[7] = f2bf(f1.w * sc);
  *(short8*)(d + i) = u.v;
}

// ---------------------------------------------------------------------------
// proj_gemm: C = A*W^T + bias. 128x128 tile, BK=32, ring-3 LDS, counted vmcnt,
// granule swizzle g^=(row>>1)&3. Grid (32,8,3): m on x (XCD-pinned A panels).
// z=0: queryb->Qp (pre-scaled CL2), z=1: keyb->Kp, z=2: valueb->Vt (transposed).
// ---------------------------------------------------------------------------
__global__ __launch_bounds__(256) void proj_gemm(
    const unsigned short* __restrict__ A0, const unsigned short* __restrict__ A1,
    const unsigned short* __restrict__ A2, const unsigned short* __restrict__ W4,
    const float* __restrict__ b0, const float* __restrict__ b1, const float* __restrict__ b2,
    unsigned short* __restrict__ Qp, unsigned short* __restrict__ Kp,
    unsigned short* __restrict__ Vt)
{
  const int z = blockIdx.z;
  const unsigned short* A = (z == 0) ? A0 : ((z == 1) ? A1 : A2);
  const unsigned short* W = W4 + (size_t)z * 1048576;
  const float* bias = (z == 0) ? b0 : ((z == 1) ? b1 : b2);
  const float esc = (z == 0) ? CL2 : 1.0f;

  const int m0 = blockIdx.x * 128;   // x = m: XCD = m%8 -> A panel pinned
  const int n0 = blockIdx.y * 128;
  const int tid = threadIdx.x;
  const int lane = tid & 63;
  const int wid = tid >> 6;
  const int wr = wid >> 1, wc = wid & 1;
  const int g = lane >> 4, l15 = lane & 15;

  __shared__ unsigned short As[3][128 * 32];
  __shared__ unsigned short Bs[3][128 * 32];

  const floatx4 vzero = {0.f, 0.f, 0.f, 0.f};
  floatx4 acc[4][4];
#pragma unroll
  for (int i = 0; i < 4; ++i)
#pragma unroll
    for (int j = 0; j < 4; ++j) acc[i][j] = vzero;

  const int lr = lane >> 2;
  const int rb0 = wid * 16, rb1 = (4 + wid) * 16;
  const int gsw0 = ((lane & 3) ^ (((rb0 + lr) >> 1) & 3)) * 8;
  const int gsw1 = ((lane & 3) ^ (((rb1 + lr) >> 1) & 3)) * 8;
  const unsigned short* pa0 = &A[(size_t)(m0 + rb0 + lr) * 1024 + gsw0];
  const unsigned short* pa1 = &A[(size_t)(m0 + rb1 + lr) * 1024 + gsw1];
  const unsigned short* pw0 = &W[(size_t)(n0 + rb0 + lr) * 1024 + gsw0];
  const unsigned short* pw1 = &W[(size_t)(n0 + rb1 + lr) * 1024 + gsw1];

#define PSTAGE(s_, b_) do { \
    gload_lds16(pa0 + (s_) * 32, &As[b_][rb0 * 32]); \
    gload_lds16(pa1 + (s_) * 32, &As[b_][rb1 * 32]); \
    gload_lds16(pw0 + (s_) * 32, &Bs[b_][rb0 * 32]); \
    gload_lds16(pw1 + (s_) * 32, &Bs[b_][rb1 * 32]); \
  } while (0)

  PSTAGE(0, 0);
  PSTAGE(1, 1);

  int cur = 0;
  for (int s = 0; s < 32; ++s) {
    if (s < 31) WAITBAR(4); else WAITBAR(0);
    if (s + 2 < 32) {
      int nb = cur + 2; if (nb >= 3) nb -= 3;
      PSTAGE(s + 2, nb);
    }

    short8 af[4], bfr[4];
#pragma unroll
    for (int mt = 0; mt < 4; ++mt) {
      const int R = wr * 64 + mt * 16 + l15;
      af[mt] = *(const short8*)&As[cur][R * 32 + ((g ^ ((R >> 1) & 3)) * 8)];
    }
#pragma unroll
    for (int nt = 0; nt < 4; ++nt) {
      const int R = wc * 64 + nt * 16 + l15;
      bfr[nt] = *(const short8*)&Bs[cur][R * 32 + ((g ^ ((R >> 1) & 3)) * 8)];
    }

    __builtin_amdgcn_s_setprio(1);
#pragma unroll
    for (int mt = 0; mt < 4; ++mt)
#pragma unroll
      for (int nt = 0; nt < 4; ++nt)
        acc[mt][nt] = MFMA16(af[mt], bfr[nt], acc[mt][nt]);
    __builtin_amdgcn_s_setprio(0);

    cur = (cur + 1 == 3) ? 0 : cur + 1;
  }
#undef PSTAGE

  float bvv[4];
#pragma unroll
  for (int nt = 0; nt < 4; ++nt) bvv[nt] = bias[n0 + wc * 64 + nt * 16 + l15] * esc;

  if (z < 2) {
    unsigned short* dst = (z == 0) ? Qp : Kp;
#pragma unroll
    for (int mt = 0; mt < 4; ++mt)
#pragma unroll
      for (int r = 0; r < 4; ++r) {
        const size_t row = (size_t)(m0 + wr * 64 + mt * 16 + g * 4 + r);
#pragma unroll
        for (int nt = 0; nt < 4; ++nt)
          dst[row * 1024 + n0 + wc * 64 + nt * 16 + l15] =
              f2bf(acc[mt][nt][r] + bvv[nt]);
      }
  } else {
#pragma unroll
    for (int mt = 0; mt < 4; ++mt) {
      const int sr = m0 + wr * 64 + mt * 16 + g * 4;
      const int bb = sr >> 11;
      const int ss = sr & 2047;
#pragma unroll
      for (int nt = 0; nt < 4; ++nt) {
        const int n = n0 + wc * 64 + nt * 16 + l15;
        const int hh = n >> 6, dd = n & 63;
        ushort4v o;
#pragma unroll
        for (int r = 0; r < 4; ++r) o[r] = f2bf(acc[mt][nt][r] + bvv[nt]);
        *(ushort4v*)&Vt[((size_t)(bb * 16 + hh) * 64 + dd) * 2048 + ss] = o;
      }
    }
  }
}

// ---------------------------------------------------------------------------
// attn_kernel: 4 waves x 32 q-rows (QBLK=128), KVBLK=64, 32x32x16, sync-dbuf,
// chain-split accumulators, exp2-domain, no max tracking.
// Grid (32,16): bh on x -> XCD = bh%8 pins each head's K/V to one XCD L2.
// ---------------------------------------------------------------------------
__global__ __launch_bounds__(256, 2) void attn_kernel(
    const unsigned short* __restrict__ Qp, const unsigned short* __restrict__ Kp,
    const unsigned short* __restrict__ Vt, unsigned short* __restrict__ X)
{
  const int bh = blockIdx.x;   // 0..31 (XCD-pinning dimension)
  const int qb = blockIdx.y;   // 0..15 (128 q-rows per block)
  const int b = bh >> 4, h = bh & 15;
  const int tid = threadIdx.x, lane = tid & 63, w = tid >> 6;
  const int l31 = lane & 31, hi = lane >> 5;

  __shared__ unsigned short KV[2][2][4096];  // [buf][K/V][64 x 64], swizzled

  const int qrow = b * 2048 + qb * 128 + w * 32 + l31;
  short8 Qf[4];
#pragma unroll
  for (int ks = 0; ks < 4; ++ks)
    Qf[ks] = *(const short8*)&Qp[(size_t)qrow * 1024 + h * 64 + ks * 16 + hi * 8];

  const int s0 = tid, s1 = tid + 256;
  const int r0 = s0 >> 3, g0 = (s0 & 7) ^ (r0 & 7);
  const int r1 = s1 >> 3, g1 = (s1 & 7) ^ (r1 & 7);
  const unsigned short* kq0 = Kp + (size_t)(b * 2048 + r0) * 1024 + h * 64 + g0 * 8;
  const unsigned short* kq1 = Kp + (size_t)(b * 2048 + r1) * 1024 + h * 64 + g1 * 8;
  const unsigned short* vq0 = Vt + (size_t)(bh * 64 + r0) * 2048 + g0 * 8;
  const unsigned short* vq1 = Vt + (size_t)(bh * 64 + r1) * 2048 + g1 * 8;
  const int db0 = (w * 64) * 8;
  const int db1 = (256 + w * 64) * 8;

  f32x16 o0a, o0b, o1a, o1b;
#pragma unroll
  for (int i = 0; i < 16; ++i) { o0a[i] = 0.f; o0b[i] = 0.f; o1a[i] = 0.f; o1b[i] = 0.f; }
  float lp4[4] = {0.f, 0.f, 0.f, 0.f};

  gload_lds16(kq0, &KV[0][0][db0]);
  gload_lds16(kq1, &KV[0][0][db1]);
  gload_lds16(vq0, &KV[0][1][db0]);
  gload_lds16(vq1, &KV[0][1][db1]);
  __syncthreads();

  int cur = 0;
  for (int t = 0; t < 32; ++t) {
    if (t + 1 < 32) {
      const size_t ko = (size_t)(t + 1) * 65536;
      const size_t vo = (size_t)(t + 1) * 64;
      gload_lds16(kq0 + ko, &KV[cur ^ 1][0][db0]);
      gload_lds16(kq1 + ko, &KV[cur ^ 1][0][db1]);
      gload_lds16(vq0 + vo, &KV[cur ^ 1][1][db0]);
      gload_lds16(vq1 + vo, &KV[cur ^ 1][1][db1]);
    }
    const unsigned short* Kb = &KV[cur][0][0];
    const unsigned short* Vb = &KV[cur][1][0];

    f32x16 c0a, c0b, c1a, c1b;
#pragma unroll
    for (int i = 0; i < 16; ++i) { c0a[i] = 0.f; c0b[i] = 0.f; c1a[i] = 0.f; c1b[i] = 0.f; }
    {
      const int kx = l31 & 7;
      const int base0 = l31 * 64;
      const int base1 = (32 + l31) * 64;
      short8 kf00 = *(const short8*)&Kb[base0 + (((0 + hi) ^ kx) << 3)];
      short8 kf01 = *(const short8*)&Kb[base0 + (((2 + hi) ^ kx) << 3)];
      short8 kf02 = *(const short8*)&Kb[base0 + (((4 + hi) ^ kx) << 3)];
      short8 kf03 = *(const short8*)&Kb[base0 + (((6 + hi) ^ kx) << 3)];
      short8 kf10 = *(const short8*)&Kb[base1 + (((0 + hi) ^ kx) << 3)];
      short8 kf11 = *(const short8*)&Kb[base1 + (((2 + hi) ^ kx) << 3)];
      short8 kf12 = *(const short8*)&Kb[base1 + (((4 + hi) ^ kx) << 3)];
      short8 kf13 = *(const short8*)&Kb[base1 + (((6 + hi) ^ kx) << 3)];
      __builtin_amdgcn_s_setprio(1);
      c0a = MFMA32(kf00, Qf[0], c0a); c0a = MFMA32(kf01, Qf[1], c0a);
      c0b = MFMA32(kf02, Qf[2], c0b); c0b = MFMA32(kf03, Qf[3], c0b);
      c1a = MFMA32(kf10, Qf[0], c1a); c1a = MFMA32(kf11, Qf[1], c1a);
      c1b = MFMA32(kf12, Qf[2], c1b); c1b = MFMA32(kf13, Qf[3], c1b);
      __builtin_amdgcn_s_setprio(0);
    }

    short8 vf0[4], vf1[4];
    {
      const int kx = l31 & 7;
      const int vrow1 = 32 + l31;
#pragma unroll
      for (int ks = 0; ks < 4; ++ks) {
        vf0[ks] = *(const short8*)&Vb[l31 * 64 + (((ks * 2 + hi) ^ kx) << 3)];
        vf1[ks] = *(const short8*)&Vb[vrow1 * 64 + (((ks * 2 + hi) ^ (vrow1 & 7)) << 3)];
      }
    }

#pragma unroll
    for (int i = 0; i < 16; ++i) {
      const float p = fast_exp2(c0a[i] + c0b[i]);
      c0a[i] = p; lp4[i & 3] += p;
    }
#pragma unroll
    for (int i = 0; i < 16; ++i) {
      const float p = fast_exp2(c1a[i] + c1b[i]);
      c1a[i] = p; lp4[i & 3] += p;
    }

    short8 PA0, PA1, PA2, PA3;
    {
      unsigned p0 = cvt_pk_bf16(c0a[0], c0a[1]),   p1 = cvt_pk_bf16(c0a[2], c0a[3]);
      unsigned p2 = cvt_pk_bf16(c0a[4], c0a[5]),   p3 = cvt_pk_bf16(c0a[6], c0a[7]);
      unsigned p4 = cvt_pk_bf16(c0a[8], c0a[9]),   p5 = cvt_pk_bf16(c0a[10], c0a[11]);
      unsigned p6 = cvt_pk_bf16(c0a[12], c0a[13]), p7 = cvt_pk_bf16(c0a[14], c0a[15]);
      PSWAP(p0, p2); PSWAP(p1, p3); PSWAP(p4, p6); PSWAP(p5, p7);
      U4 a_, b_;
      a_.w[0] = p0; a_.w[1] = p1; a_.w[2] = p2; a_.w[3] = p3;      PA0 = a_.v;
      b_.w[0] = p4; b_.w[1] = p5; b_.w[2] = p6; b_.w[3] = p7;      PA1 = b_.v;
    }
    {
      unsigned p0 = cvt_pk_bf16(c1a[0], c1a[1]),   p1 = cvt_pk_bf16(c1a[2], c1a[3]);
      unsigned p2 = cvt_pk_bf16(c1a[4], c1a[5]),   p3 = cvt_pk_bf16(c1a[6], c1a[7]);
      unsigned p4 = cvt_pk_bf16(c1a[8], c1a[9]),   p5 = cvt_pk_bf16(c1a[10], c1a[11]);
      unsigned p6 = cvt_pk_bf16(c1a[12], c1a[13]), p7 = cvt_pk_bf16(c1a[14], c1a[15]);
      PSWAP(p0, p2); PSWAP(p1, p3); PSWAP(p4, p6); PSWAP(p5, p7);
      U4 a_, b_;
      a_.w[0] = p0; a_.w[1] = p1; a_.w[2] = p2; a_.w[3] = p3;      PA2 = a_.v;
      b_.w[0] = p4; b_.w[1] = p5; b_.w[2] = p6; b_.w[3] = p7;      PA3 = b_.v;
    }

    __builtin_amdgcn_s_setprio(1);
    o0a = MFMA32(vf0[0], PA0, o0a); o0a = MFMA32(vf0[1], PA1, o0a);
    o0b = MFMA32(vf0[2], PA2, o0b); o0b = MFMA32(vf0[3], PA3, o0b);
    o1a = MFMA32(vf1[0], PA0, o1a); o1a = MFMA32(vf1[1], PA1, o1a);
    o1b = MFMA32(vf1[2], PA2, o1b); o1b = MFMA32(vf1[3], PA3, o1b);
    __builtin_amdgcn_s_setprio(0);

    __syncthreads();
    cur ^= 1;
  }

  const float l_run = (lp4[0] + lp4[1]) + (lp4[2] + lp4[3]);
  const float l_tot = l_run + __shfl_xor(l_run, 32);
  const float linv = 1.f / l_tot;
#pragma unroll
  for (int a = 0; a < 4; ++a) {
    ushort4v v0, v1;
#pragma unroll
    for (int r = 0; r < 4; ++r) {
      v0[r] = f2bf((o0a[a * 4 + r] + o0b[a * 4 + r]) * linv);
      v1[r] = f2bf((o1a[a * 4 + r] + o1b[a * 4 + r]) * linv);
    }
    *(ushort4v*)&X[(size_t)qrow * 1024 + h * 64 + a * 8 + hi * 4] = v0;
    *(ushort4v*)&X[(size_t)qrow * 1024 + h * 64 + 32 + a * 8 + hi * 4] = v1;
  }
}

// ---------------------------------------------------------------------------
// out_gemm: out = X*Wo^T + bo (fp32). BM=64, BN=128, BK=32 ring-3, counted
// vmcnt(3), granule swizzle. Grid (64,8): m on x (XCD-pinned X panels).
// ---------------------------------------------------------------------------
__global__ __launch_bounds__(256) void out_gemm(
    const unsigned short* __restrict__ A, const unsigned short* __restrict__ W,
    const float* __restrict__ bias, float* __restrict__ out)
{
  const int m0 = blockIdx.x * 64;    // x = m: XCD-pinned X panels
  const int n0 = blockIdx.y * 128;
  const int tid = threadIdx.x;
  const int lane = tid & 63;
  const int wid = tid >> 6;
  const int wr = wid >> 1, wc = wid & 1;
  const int g = lane >> 4, l15 = lane & 15;

  __shared__ unsigned short As[3][64 * 32];
  __shared__ unsigned short Bs[3][128 * 32];

  const floatx4 vzero = {0.f, 0.f, 0.f, 0.f};
  floatx4 acc[2][4];
#pragma unroll
  for (int i = 0; i < 2; ++i)
#pragma unroll
    for (int j = 0; j < 4; ++j) acc[i][j] = vzero;

  const int lr = lane >> 2;
  const int rb0 = wid * 16, rb1 = (4 + wid) * 16;
  const int gsw0 = ((lane & 3) ^ (((rb0 + lr) >> 1) & 3)) * 8;
  const int gsw1 = ((lane & 3) ^ (((rb1 + lr) >> 1) & 3)) * 8;
  const unsigned short* pa0 = &A[(size_t)(m0 + rb0 + lr) * 1024 + gsw0];
  const unsigned short* pw0 = &W[(size_t)(n0 + rb0 + lr) * 1024 + gsw0];
  const unsigned short* pw1 = &W[(size_t)(n0 + rb1 + lr) * 1024 + gsw1];

#define OSTAGE(s_, b_) do { \
    gload_lds16(pa0 + (s_) * 32, &As[b_][rb0 * 32]); \
    gload_lds16(pw0 + (s_) * 32, &Bs[b_][rb0 * 32]); \
    gload_lds16(pw1 + (s_) * 32, &Bs[b_][rb1 * 32]); \
  } while (0)

  OSTAGE(0, 0);
  OSTAGE(1, 1);

  int cur = 0;
  for (int s = 0; s < 32; ++s) {
    if (s < 31) WAITBAR(3); else WAITBAR(0);
    if (s + 2 < 32) {
      int nb = cur + 2; if (nb >= 3) nb -= 3;
      OSTAGE(s + 2, nb);
    }

    short8 af[2], bfr[4];
#pragma unroll
    for (int mt = 0; mt < 2; ++mt) {
      const int R = wr * 32 + mt * 16 + l15;
      af[mt] = *(const short8*)&As[cur][R * 32 + ((g ^ ((R >> 1) & 3)) * 8)];
    }
#pragma unroll
    for (int nt = 0; nt < 4; ++nt) {
      const int R = wc * 64 + nt * 16 + l15;
      bfr[nt] = *(const short8*)&Bs[cur][R * 32 + ((g ^ ((R >> 1) & 3)) * 8)];
    }

    __builtin_amdgcn_s_setprio(1);
#pragma unroll
    for (int mt = 0; mt < 2; ++mt)
#pragma unroll
      for (int nt = 0; nt < 4; ++nt)
        acc[mt][nt] = MFMA16(af[mt], bfr[nt], acc[mt][nt]);
    __builtin_amdgcn_s_setprio(0);

    cur = (cur + 1 == 3) ? 0 : cur + 1;
  }
#undef OSTAGE

  float bvv[4];
#pragma unroll
  for (int nt = 0; nt < 4; ++nt) bvv[nt] = bias[n0 + wc * 64 + nt * 16 + l15];

#pragma unroll
  for (int mt = 0; mt < 2; ++mt)
#pragma unroll
    for (int r = 0; r < 4; ++r) {
      const size_t row = (size_t)(m0 + wr * 32 + mt * 16 + g * 4 + r);
#pragma unroll
      for (int nt = 0; nt < 4; ++nt)
        out[row * 1024 + n0 + wc * 64 + nt * 16 + l15] = acc[mt][nt][r] + bvv[nt];
    }
}

// ---------------------------------------------------------------------------
extern "C" void kernel_launch(void* const* d_in, const int* in_sizes, int n_in,
                              void* d_out, int out_size, void* d_ws, size_t ws_size,
                              hipStream_t stream)
{
  const float* query = (const float*)d_in[0];
  const float* value = (const float*)d_in[1];
  const float* key   = (const float*)d_in[2];
  const float* Wq = (const float*)d_in[3];
  const float* bq = (const float*)d_in[4];
  const float* Wk = (const float*)d_in[5];
  const float* bk = (const float*)d_in[6];
  const float* Wv = (const float*)d_in[7];
  const float* bv = (const float*)d_in[8];
  const float* Wo = (const float*)d_in[9];
  const float* bo = (const float*)d_in[10];
  float* out = (float*)d_out;

  const size_t M4 = (size_t)4096 * 1024;
  unsigned short* vb = (unsigned short*)d_ws;
  unsigned short* w4 = vb + M4;
  unsigned short* Qp = w4 + M4;
  unsigned short* Kp = Qp + M4;
  unsigned short* Vt = Kp + M4;
  unsigned short* X  = vb;  // alias (valueb dead after proj)
  unsigned short* qb = (unsigned short*)d_out;  // d_out scratch
  unsigned short* kb = qb + M4;

  convert_all<<<8192, 256, 0, stream>>>(query, key, value, Wq, Wk, Wv, Wo,
                                        qb, kb, vb, w4);
  proj_gemm<<<dim3(32, 8, 3), 256, 0, stream>>>(qb, kb, vb, w4,
                                                bq, bk, bv, Qp, Kp, Vt);
  attn_kernel<<<dim3(32, 16), 256, 0, stream>>>(Qp, Kp, Vt, X);
  out_gemm<<<dim3(64, 8), 256, 0, stream>>>(X, w4 + 3 * 1048576, bo, out);
}